// Round 1
// baseline (1515.494 us; speedup 1.0000x reference)
//
#include <hip/hip_runtime.h>

typedef unsigned short u16;
typedef unsigned int u32;
typedef __bf16 bf16x8 __attribute__((ext_vector_type(8)));
typedef float f32x4 __attribute__((ext_vector_type(4)));

#define HH 32
#define KVHH 8
#define DD 128
#define HID 4096
#define SCALE_Q 0.08838834764831845f // 128^-0.5

static __device__ __forceinline__ float bf2f(u32 u) { u <<= 16; return __builtin_bit_cast(float, u); }
static __device__ __forceinline__ u16 f2bf(float f) {
  u32 x = __builtin_bit_cast(u32, f);
  return (u16)((x + 0x7fffu + ((x >> 16) & 1u)) >> 16);
}
static __device__ __forceinline__ void gll16(const void* g, void* l) {
  __builtin_amdgcn_global_load_lds((const __attribute__((address_space(1))) void*)g,
                                   (__attribute__((address_space(3))) void*)l, 16, 0, 0);
}
static __device__ __forceinline__ f32x4 mfma16(bf16x8 a, bf16x8 b, f32x4 c) {
  return __builtin_amdgcn_mfma_f32_16x16x32_bf16(a, b, c, 0, 0, 0);
}

// ---------------- elementwise f32 -> bf16 ----------------
__global__ __launch_bounds__(256) void cvt_f32_bf16(const float* __restrict__ in, u16* __restrict__ out, size_t n4) {
  size_t i = (size_t)blockIdx.x * blockDim.x + threadIdx.x;
  size_t stride = (size_t)gridDim.x * blockDim.x;
  for (; i < n4; i += stride) {
    float4 v = ((const float4*)in)[i];
    ushort4 o;
    o.x = f2bf(v.x); o.y = f2bf(v.y); o.z = f2bf(v.z); o.w = f2bf(v.w);
    ((ushort4*)out)[i] = o;
  }
}

// ---------------- transpose + convert: out[N][K] bf16 = in[K][N] f32 ----------------
__global__ __launch_bounds__(256) void transpose_cvt(const float* __restrict__ in, u16* __restrict__ out, int K, int N) {
  __shared__ float t[64][68];
  int k0 = blockIdx.x * 64, n0 = blockIdx.y * 64;
  int tid = threadIdx.x;
  int r = tid >> 4, c4 = (tid & 15) << 2;
#pragma unroll
  for (int i = 0; i < 4; ++i) {
    float4 v = *(const float4*)(in + (size_t)(k0 + r + i * 16) * N + n0 + c4);
    t[r + i * 16][c4 + 0] = v.x; t[r + i * 16][c4 + 1] = v.y;
    t[r + i * 16][c4 + 2] = v.z; t[r + i * 16][c4 + 3] = v.w;
  }
  __syncthreads();
#pragma unroll
  for (int i = 0; i < 4; ++i) {
    int rr = r + i * 16;
    ushort4 o;
    o.x = f2bf(t[c4 + 0][rr]); o.y = f2bf(t[c4 + 1][rr]);
    o.z = f2bf(t[c4 + 2][rr]); o.w = f2bf(t[c4 + 3][rr]);
    *(ushort4*)(out + (size_t)(n0 + rr) * K + k0 + c4) = o;
  }
}

// ---------------- bf16 transpose (for V): out[n][m] = in[m][colOff+n] ----------------
__global__ __launch_bounds__(256) void transpose_bf(const u16* __restrict__ in, u16* __restrict__ out,
                                                    int ldin, int colOff, int ldout) {
  __shared__ u16 t[64][72];
  int m0 = blockIdx.x * 64, n0 = blockIdx.y * 64;
  int tid = threadIdx.x;
  int r = tid >> 4, c4 = (tid & 15) << 2;
#pragma unroll
  for (int i = 0; i < 4; ++i) {
    ushort4 v = *(const ushort4*)(in + (size_t)(m0 + r + i * 16) * ldin + colOff + n0 + c4);
    t[r + i * 16][c4 + 0] = v.x; t[r + i * 16][c4 + 1] = v.y;
    t[r + i * 16][c4 + 2] = v.z; t[r + i * 16][c4 + 3] = v.w;
  }
  __syncthreads();
#pragma unroll
  for (int i = 0; i < 4; ++i) {
    int rr = r + i * 16;
    ushort4 o;
    o.x = t[c4 + 0][rr]; o.y = t[c4 + 1][rr]; o.z = t[c4 + 2][rr]; o.w = t[c4 + 3][rr];
    *(ushort4*)(out + (size_t)(n0 + rr) * ldout + m0 + c4) = o;
  }
}

// ---------------- RMS norm (in-place bf16), one wave per (row, head) ----------------
__global__ __launch_bounds__(256) void rmsnorm_kernel(u16* __restrict__ x, const float* __restrict__ w,
                                                      int totalRows, int heads, int ld, float scale) {
  int gw = blockIdx.x * 4 + (threadIdx.x >> 6);
  if (gw >= totalRows) return;
  int lane = threadIdx.x & 63;
  int row = gw / heads, h = gw - row * heads;
  u16* p = x + (size_t)row * ld + h * 128 + lane * 2;
  u32 u = *(const u32*)p;
  float a = bf2f(u & 0xffffu), b = bf2f(u >> 16);
  float ss = a * a + b * b;
#pragma unroll
  for (int o = 1; o < 64; o <<= 1) ss += __shfl_xor(ss, o);
  float inv = rsqrtf(ss * (1.0f / 128.0f) + 1e-5f) * scale;
  float oa = a * inv * w[lane * 2], ob = b * inv * w[lane * 2 + 1];
  *(u32*)p = (u32)f2bf(oa) | ((u32)f2bf(ob) << 16);
}

// ---------------- GEMM: C[M][N] = A[M][K] * B^T (B stored [N][K]), 128x128 tile, BK=64 ----------------
template <int STOREF32, int CLAMP>
__global__ __launch_bounds__(256, 2) void gemm_bt(const u16* __restrict__ A, const u16* __restrict__ B,
                                                  void* __restrict__ C, int N, int K, int Mclamp, int Mstore) {
  __shared__ __align__(16) char As[16384]; // 128 rows x 128B (64 bf16), XOR-swizzled
  __shared__ __align__(16) char Bs[16384];
  const int tid = threadIdx.x, lane = tid & 63, wave = tid >> 6;
  const int wr = wave >> 1, wc = wave & 1;
  const int l15 = lane & 15, lg = lane >> 4;
  const int m0 = blockIdx.x * 128, n0 = blockIdx.y * 128;
  f32x4 acc[4][4] = {};
  const int kIters = K >> 6;
  int srow[4], scb[4], sbase[4];
#pragma unroll
  for (int q = 0; q < 4; ++q) {
    sbase[q] = (wave * 4 + q) * 1024;
    int off = sbase[q] + lane * 16;
    srow[q] = off >> 7;
    scb[q] = (off & 127) ^ ((srow[q] & 7) << 4); // pre-swizzled source -> linear LDS dest
  }
  for (int kt = 0; kt < kIters; ++kt) {
    __syncthreads();
#pragma unroll
    for (int q = 0; q < 4; ++q) {
      int ar = m0 + srow[q];
      if (CLAMP) ar = min(ar, Mclamp - 1);
      gll16(A + (size_t)ar * K + kt * 64 + (scb[q] >> 1), As + sbase[q]);
      gll16(B + (size_t)(n0 + srow[q]) * K + kt * 64 + (scb[q] >> 1), Bs + sbase[q]);
    }
    __syncthreads();
#pragma unroll
    for (int kk = 0; kk < 2; ++kk) {
      bf16x8 af[4], bfr[4];
#pragma unroll
      for (int mt = 0; mt < 4; ++mt) {
        int rr = wr * 64 + mt * 16 + l15;
        int cb = ((kk * 32 + lg * 8) * 2) ^ ((rr & 7) << 4);
        af[mt] = *(const bf16x8*)(As + rr * 128 + cb);
      }
#pragma unroll
      for (int nt = 0; nt < 4; ++nt) {
        int rr = wc * 64 + nt * 16 + l15;
        int cb = ((kk * 32 + lg * 8) * 2) ^ ((rr & 7) << 4);
        bfr[nt] = *(const bf16x8*)(Bs + rr * 128 + cb);
      }
#pragma unroll
      for (int mt = 0; mt < 4; ++mt)
#pragma unroll
        for (int nt = 0; nt < 4; ++nt)
          acc[mt][nt] = mfma16(af[mt], bfr[nt], acc[mt][nt]);
    }
  }
#pragma unroll
  for (int mt = 0; mt < 4; ++mt) {
#pragma unroll
    for (int nt = 0; nt < 4; ++nt) {
      int cc = n0 + wc * 64 + nt * 16 + l15;
#pragma unroll
      for (int j = 0; j < 4; ++j) {
        int cr = m0 + wr * 64 + mt * 16 + lg * 4 + j;
        if (CLAMP && cr >= Mstore) continue;
        if (STOREF32) ((float*)C)[(size_t)cr * N + cc] = acc[mt][nt][j];
        else ((u16*)C)[(size_t)cr * N + cc] = f2bf(acc[mt][nt][j]);
      }
    }
  }
}

// ---------------- fused GQA cross-attention ----------------
// grid (q_len/64, 32 heads); block 256 = 4 waves; each wave owns 16 q rows.
__global__ __launch_bounds__(256, 2) void attn_kernel(const u16* __restrict__ q, const u16* __restrict__ kv,
                                                      const u16* __restrict__ vT, const float* __restrict__ mask,
                                                      u16* __restrict__ out, int kv_len, int kv_tiles, int kvp) {
  __shared__ __align__(16) char Ks[64 * 256];  // K tile, rows 256B, XOR-swizzled ((row&15)<<4)
  __shared__ __align__(16) char Vs[128 * 128]; // V^T tile, rows 128B, XOR-swizzled ((row&7)<<4)
  __shared__ __align__(16) u16 Ps[4][16][72];  // per-wave P, padded stride 72
  const int tid = threadIdx.x, lane = tid & 63, wave = tid >> 6;
  const int l15 = lane & 15, lg = lane >> 4;
  const int h = blockIdx.y, kvh = h >> 2;
  const int qb = blockIdx.x * 64 + wave * 16;

  bf16x8 qa[4];
  {
    const u16* qp = q + (size_t)(qb + l15) * 4096 + h * 128 + lg * 8;
    qa[0] = *(const bf16x8*)(qp);
    qa[1] = *(const bf16x8*)(qp + 32);
    qa[2] = *(const bf16x8*)(qp + 64);
    qa[3] = *(const bf16x8*)(qp + 96);
  }
  f32x4 o[8] = {};
  float m_r[4], l_r[4];
#pragma unroll
  for (int j = 0; j < 4; ++j) { m_r[j] = -1e30f; l_r[j] = 0.0f; }

  for (int t = 0; t < kv_tiles; ++t) {
    const int kt0 = t * 64;
    __syncthreads(); // previous PV reads of Ks/Vs done
#pragma unroll
    for (int qq = 0; qq < 4; ++qq) {
      int base = (wave * 4 + qq) * 1024;
      int off = base + lane * 16;
      {
        int row = off >> 8;
        int cb = (off & 255) ^ ((row & 15) << 4);
        gll16(kv + (size_t)(kt0 + row) * 2048 + kvh * 128 + (cb >> 1), Ks + base);
      }
      {
        int row = off >> 7;
        int cb = (off & 127) ^ ((row & 7) << 4);
        gll16(vT + (size_t)(kvh * 128 + row) * kvp + kt0 + (cb >> 1), Vs + base);
      }
    }
    __syncthreads();
    // S = Q K^T   (each wave: 16 q rows x 64 kv)
    f32x4 s[4] = {};
#pragma unroll
    for (int kk = 0; kk < 4; ++kk)
#pragma unroll
      for (int c = 0; c < 4; ++c) {
        int rr = c * 16 + l15;
        int cb = ((kk * 32 + lg * 8) * 2) ^ ((rr & 15) << 4);
        bf16x8 b = *(const bf16x8*)(Ks + rr * 256 + cb);
        s[c] = mfma16(qa[kk], b, s[c]);
      }
    // mask + kv padding
#pragma unroll
    for (int c = 0; c < 4; ++c) {
      int kvi = kt0 + c * 16 + l15;
      bool valid = kvi < kv_len;
      const float* mp = mask + (size_t)(qb + lg * 4) * kv_len + kvi;
#pragma unroll
      for (int j = 0; j < 4; ++j)
        s[c][j] = valid ? s[c][j] + mp[(size_t)j * kv_len] : -1e30f;
    }
    // online softmax per q row (rows live in 16-lane groups)
#pragma unroll
    for (int j = 0; j < 4; ++j) {
      float tm = fmaxf(fmaxf(s[0][j], s[1][j]), fmaxf(s[2][j], s[3][j]));
      tm = fmaxf(tm, __shfl_xor(tm, 1));
      tm = fmaxf(tm, __shfl_xor(tm, 2));
      tm = fmaxf(tm, __shfl_xor(tm, 4));
      tm = fmaxf(tm, __shfl_xor(tm, 8));
      float mn = fmaxf(m_r[j], tm);
      float alpha = __expf(m_r[j] - mn);
      m_r[j] = mn;
      float rs = 0.0f;
#pragma unroll
      for (int c = 0; c < 4; ++c) {
        float p = __expf(s[c][j] - mn);
        s[c][j] = p;
        rs += p;
      }
      rs += __shfl_xor(rs, 1);
      rs += __shfl_xor(rs, 2);
      rs += __shfl_xor(rs, 4);
      rs += __shfl_xor(rs, 8);
      l_r[j] = l_r[j] * alpha + rs;
#pragma unroll
      for (int dt = 0; dt < 8; ++dt) o[dt][j] *= alpha;
#pragma unroll
      for (int c = 0; c < 4; ++c) Ps[wave][lg * 4 + j][c * 16 + l15] = f2bf(s[c][j]);
    }
    // O += P V  (P from per-wave LDS; no cross-wave barrier needed)
#pragma unroll
    for (int kk2 = 0; kk2 < 2; ++kk2) {
      bf16x8 a = *(const bf16x8*)&Ps[wave][l15][kk2 * 32 + lg * 8];
#pragma unroll
      for (int dt = 0; dt < 8; ++dt) {
        int rr = dt * 16 + l15;
        int cb = ((kk2 * 32 + lg * 8) * 2) ^ ((rr & 7) << 4);
        bf16x8 b = *(const bf16x8*)(Vs + rr * 128 + cb);
        o[dt] = mfma16(a, b, o[dt]);
      }
    }
  }
#pragma unroll
  for (int j = 0; j < 4; ++j) {
    float inv = 1.0f / l_r[j];
    u16* op = out + (size_t)(qb + lg * 4 + j) * 4096 + h * 128 + l15;
#pragma unroll
    for (int dt = 0; dt < 8; ++dt) op[dt * 16] = f2bf(o[dt][j] * inv);
  }
}

extern "C" void kernel_launch(void* const* d_in, const int* in_sizes, int n_in,
                              void* d_out, int out_size, void* d_ws, size_t ws_size,
                              hipStream_t stream) {
  const float* hidden = (const float*)d_in[0];
  const float* cross = (const float*)d_in[1];
  const float* mask = (const float*)d_in[2];
  const float* w_qkv = (const float*)d_in[3];
  const float* w_o = (const float*)d_in[4];
  const float* q_norm_w = (const float*)d_in[5];
  const float* k_norm_w = (const float*)d_in[6];
  const int q_len = in_sizes[0] / HID;            // 1024
  const int kv_len = in_sizes[1] / HID;           // 6404
  const int kvp = ((kv_len + 127) / 128) * 128;   // 6528
  const int kv_tiles = (kv_len + 63) / 64;        // 101

  char* w = (char*)d_ws;
  u16* hB = (u16*)w;    w += (size_t)q_len * HID * 2;
  u16* cB = (u16*)w;    w += (size_t)kv_len * HID * 2;
  u16* wqkvT = (u16*)w; w += (size_t)6144 * 4096 * 2;
  u16* woT = (u16*)w;   w += (size_t)4096 * 4096 * 2;
  u16* qrw = (u16*)w;   w += (size_t)q_len * 4096 * 2;
  u16* kvr = (u16*)w;   w += (size_t)kvp * 2048 * 2;
  u16* vT = (u16*)w;    w += (size_t)1024 * kvp * 2;
  u16* aO = (u16*)w;    w += (size_t)q_len * 4096 * 2;

  cvt_f32_bf16<<<1024, 256, 0, stream>>>(hidden, hB, (size_t)q_len * HID / 4);
  cvt_f32_bf16<<<2048, 256, 0, stream>>>(cross, cB, (size_t)kv_len * HID / 4);
  transpose_cvt<<<dim3(64, 96), 256, 0, stream>>>(w_qkv, wqkvT, 4096, 6144);
  transpose_cvt<<<dim3(64, 64), 256, 0, stream>>>(w_o, woT, 4096, 4096);

  // q projection + RMS norm (SCALE folded in)
  gemm_bt<0, 0><<<dim3(q_len / 128, 32), 256, 0, stream>>>(hB, wqkvT, qrw, 4096, 4096, 0, 0);
  rmsnorm_kernel<<<(q_len * 32 + 3) / 4, 256, 0, stream>>>(qrw, q_norm_w, q_len * 32, 32, 4096, SCALE_Q);

  // kv projection (rows clamped to kv_len, padded rows stored as dups) + k norm + V transpose
  gemm_bt<0, 1><<<dim3(kvp / 128, 16), 256, 0, stream>>>(cB, wqkvT + (size_t)4096 * 4096, kvr, 2048, 4096, kv_len, kvp);
  rmsnorm_kernel<<<(kvp * 8 + 3) / 4, 256, 0, stream>>>(kvr, k_norm_w, kvp * 8, 8, 2048, 1.0f);
  transpose_bf<<<dim3(kvp / 64, 16), 256, 0, stream>>>(kvr, vT, 2048, 1024, kvp);

  attn_kernel<<<dim3(q_len / 64, HH), 256, 0, stream>>>(qrw, kvr, vT, mask, aO, kv_len, kv_tiles, kvp);

  gemm_bt<1, 0><<<dim3(q_len / 128, 32), 256, 0, stream>>>(aO, woT, d_out, 4096, 4096, 0, 0);
}

// Round 2
// 927.087 us; speedup vs baseline: 1.6347x; 1.6347x over previous
//
#include <hip/hip_runtime.h>

typedef unsigned short u16;
typedef unsigned int u32;
typedef __bf16 bf16x8 __attribute__((ext_vector_type(8)));
typedef float f32x4 __attribute__((ext_vector_type(4)));

#define HH 32
#define KVHH 8
#define DD 128
#define HID 4096
#define SCALE_Q 0.08838834764831845f // 128^-0.5

static __device__ __forceinline__ float bf2f(u32 u) { u <<= 16; return __builtin_bit_cast(float, u); }
static __device__ __forceinline__ u16 f2bf(float f) {
  u32 x = __builtin_bit_cast(u32, f);
  return (u16)((x + 0x7fffu + ((x >> 16) & 1u)) >> 16);
}
static __device__ __forceinline__ void gll16(const void* g, void* l) {
  __builtin_amdgcn_global_load_lds((const __attribute__((address_space(1))) void*)g,
                                   (__attribute__((address_space(3))) void*)l, 16, 0, 0);
}
static __device__ __forceinline__ f32x4 mfma16(bf16x8 a, bf16x8 b, f32x4 c) {
  return __builtin_amdgcn_mfma_f32_16x16x32_bf16(a, b, c, 0, 0, 0);
}

// ---------------- elementwise f32 -> bf16 ----------------
__global__ __launch_bounds__(256) void cvt_f32_bf16(const float* __restrict__ in, u16* __restrict__ out, size_t n4) {
  size_t i = (size_t)blockIdx.x * blockDim.x + threadIdx.x;
  size_t stride = (size_t)gridDim.x * blockDim.x;
  for (; i < n4; i += stride) {
    float4 v = ((const float4*)in)[i];
    ushort4 o;
    o.x = f2bf(v.x); o.y = f2bf(v.y); o.z = f2bf(v.z); o.w = f2bf(v.w);
    ((ushort4*)out)[i] = o;
  }
}

// ---------------- transpose + convert: out[N][K] bf16 = in[K][N] f32 ----------------
__global__ __launch_bounds__(256) void transpose_cvt(const float* __restrict__ in, u16* __restrict__ out, int K, int N) {
  __shared__ float t[64][68];
  int k0 = blockIdx.x * 64, n0 = blockIdx.y * 64;
  int tid = threadIdx.x;
  int r = tid >> 4, c4 = (tid & 15) << 2;
#pragma unroll
  for (int i = 0; i < 4; ++i) {
    float4 v = *(const float4*)(in + (size_t)(k0 + r + i * 16) * N + n0 + c4);
    t[r + i * 16][c4 + 0] = v.x; t[r + i * 16][c4 + 1] = v.y;
    t[r + i * 16][c4 + 2] = v.z; t[r + i * 16][c4 + 3] = v.w;
  }
  __syncthreads();
#pragma unroll
  for (int i = 0; i < 4; ++i) {
    int rr = r + i * 16;
    ushort4 o;
    o.x = f2bf(t[c4 + 0][rr]); o.y = f2bf(t[c4 + 1][rr]);
    o.z = f2bf(t[c4 + 2][rr]); o.w = f2bf(t[c4 + 3][rr]);
    *(ushort4*)(out + (size_t)(n0 + rr) * K + k0 + c4) = o;
  }
}

// ---------------- bf16 transpose (for V): out[n][m] = in[m][colOff+n] ----------------
__global__ __launch_bounds__(256) void transpose_bf(const u16* __restrict__ in, u16* __restrict__ out,
                                                    int ldin, int colOff, int ldout) {
  __shared__ u16 t[64][72];
  int m0 = blockIdx.x * 64, n0 = blockIdx.y * 64;
  int tid = threadIdx.x;
  int r = tid >> 4, c4 = (tid & 15) << 2;
#pragma unroll
  for (int i = 0; i < 4; ++i) {
    ushort4 v = *(const ushort4*)(in + (size_t)(m0 + r + i * 16) * ldin + colOff + n0 + c4);
    t[r + i * 16][c4 + 0] = v.x; t[r + i * 16][c4 + 1] = v.y;
    t[r + i * 16][c4 + 2] = v.z; t[r + i * 16][c4 + 3] = v.w;
  }
  __syncthreads();
#pragma unroll
  for (int i = 0; i < 4; ++i) {
    int rr = r + i * 16;
    ushort4 o;
    o.x = t[c4 + 0][rr]; o.y = t[c4 + 1][rr]; o.z = t[c4 + 2][rr]; o.w = t[c4 + 3][rr];
    *(ushort4*)(out + (size_t)(n0 + rr) * ldout + m0 + c4) = o;
  }
}

// ---------------- RMS norm (in-place bf16), one wave per (row, head) ----------------
__global__ __launch_bounds__(256) void rmsnorm_kernel(u16* __restrict__ x, const float* __restrict__ w,
                                                      int totalRows, int heads, int ld, float scale) {
  int gw = blockIdx.x * 4 + (threadIdx.x >> 6);
  if (gw >= totalRows) return;
  int lane = threadIdx.x & 63;
  int row = gw / heads, h = gw - row * heads;
  u16* p = x + (size_t)row * ld + h * 128 + lane * 2;
  u32 u = *(const u32*)p;
  float a = bf2f(u & 0xffffu), b = bf2f(u >> 16);
  float ss = a * a + b * b;
#pragma unroll
  for (int o = 1; o < 64; o <<= 1) ss += __shfl_xor(ss, o);
  float inv = rsqrtf(ss * (1.0f / 128.0f) + 1e-5f) * scale;
  float oa = a * inv * w[lane * 2], ob = b * inv * w[lane * 2 + 1];
  *(u32*)p = (u32)f2bf(oa) | ((u32)f2bf(ob) << 16);
}

// ---------------- GEMM: C[M][N] = A[M][K] * B^T (B stored [N][K]), 128x128 tile, BK=64 ----------------
template <int STOREF32, int CLAMP>
__global__ __launch_bounds__(256, 2) void gemm_bt(const u16* __restrict__ A, const u16* __restrict__ B,
                                                  void* __restrict__ C, int N, int K, int Mclamp, int Mstore) {
  __shared__ __align__(16) char As[16384]; // 128 rows x 128B (64 bf16), XOR-swizzled
  __shared__ __align__(16) char Bs[16384];
  const int tid = threadIdx.x, lane = tid & 63, wave = tid >> 6;
  const int wr = wave >> 1, wc = wave & 1;
  const int l15 = lane & 15, lg = lane >> 4;
  const int m0 = blockIdx.x * 128, n0 = blockIdx.y * 128;
  f32x4 acc[4][4] = {};
  const int kIters = K >> 6;
  int srow[4], scb[4], sbase[4];
#pragma unroll
  for (int q = 0; q < 4; ++q) {
    sbase[q] = (wave * 4 + q) * 1024;
    int off = sbase[q] + lane * 16;
    srow[q] = off >> 7;
    scb[q] = (off & 127) ^ ((srow[q] & 7) << 4); // pre-swizzled source -> linear LDS dest
  }
  for (int kt = 0; kt < kIters; ++kt) {
    __syncthreads();
#pragma unroll
    for (int q = 0; q < 4; ++q) {
      int ar = m0 + srow[q];
      if (CLAMP) ar = min(ar, Mclamp - 1);
      gll16(A + (size_t)ar * K + kt * 64 + (scb[q] >> 1), As + sbase[q]);
      gll16(B + (size_t)(n0 + srow[q]) * K + kt * 64 + (scb[q] >> 1), Bs + sbase[q]);
    }
    __syncthreads();
#pragma unroll
    for (int kk = 0; kk < 2; ++kk) {
      bf16x8 af[4], bfr[4];
#pragma unroll
      for (int mt = 0; mt < 4; ++mt) {
        int rr = wr * 64 + mt * 16 + l15;
        int cb = ((kk * 32 + lg * 8) * 2) ^ ((rr & 7) << 4);
        af[mt] = *(const bf16x8*)(As + rr * 128 + cb);
      }
#pragma unroll
      for (int nt = 0; nt < 4; ++nt) {
        int rr = wc * 64 + nt * 16 + l15;
        int cb = ((kk * 32 + lg * 8) * 2) ^ ((rr & 7) << 4);
        bfr[nt] = *(const bf16x8*)(Bs + rr * 128 + cb);
      }
#pragma unroll
      for (int mt = 0; mt < 4; ++mt)
#pragma unroll
        for (int nt = 0; nt < 4; ++nt)
          acc[mt][nt] = mfma16(af[mt], bfr[nt], acc[mt][nt]);
    }
  }
#pragma unroll
  for (int mt = 0; mt < 4; ++mt) {
#pragma unroll
    for (int nt = 0; nt < 4; ++nt) {
      int cc = n0 + wc * 64 + nt * 16 + l15;
#pragma unroll
      for (int j = 0; j < 4; ++j) {
        int cr = m0 + wr * 64 + mt * 16 + lg * 4 + j;
        if (CLAMP && cr >= Mstore) continue;
        if (STOREF32) ((float*)C)[(size_t)cr * N + cc] = acc[mt][nt][j];
        else ((u16*)C)[(size_t)cr * N + cc] = f2bf(acc[mt][nt][j]);
      }
    }
  }
}

// ---------------- fused GQA cross-attention (split-KV, double-buffered) ----------------
// grid (q_len/64, 32 heads, NSPLIT); block 256 = 4 waves; each wave owns 16 q rows.
// Writes UNNORMALIZED partial O (f32) + (m,l) per row; combine kernel merges splits.
__global__ __launch_bounds__(256, 2) void attn_kernel(const u16* __restrict__ q, const u16* __restrict__ kv,
                                                      const u16* __restrict__ vT, const float* __restrict__ mask,
                                                      float* __restrict__ pO, float2* __restrict__ ml,
                                                      int kv_len, int kv_tiles, int kvp, int tiles_per_split) {
  __shared__ __align__(16) char Ks[2][16384];  // K tile, rows 256B, XOR-swizzled ((row&15)<<4)
  __shared__ __align__(16) char Vs[2][16384];  // V^T tile, rows 128B, XOR-swizzled ((row&7)<<4)
  __shared__ __align__(16) u16 Ps[4][16][72];  // per-wave P, padded stride 72
  const int tid = threadIdx.x, lane = tid & 63, wave = tid >> 6;
  const int l15 = lane & 15, lg = lane >> 4;
  const int h = blockIdx.y, kvh = h >> 2;
  const int qb = blockIdx.x * 64 + wave * 16;
  const int split = blockIdx.z;
  const int t0 = split * tiles_per_split;
  const int t1 = min(t0 + tiles_per_split, kv_tiles);

  bf16x8 qa[4];
  {
    const u16* qp = q + (size_t)(qb + l15) * 4096 + h * 128 + lg * 8;
    qa[0] = *(const bf16x8*)(qp);
    qa[1] = *(const bf16x8*)(qp + 32);
    qa[2] = *(const bf16x8*)(qp + 64);
    qa[3] = *(const bf16x8*)(qp + 96);
  }
  int base[4], krow[4], kcb[4], vrow[4], vcb[4];
#pragma unroll
  for (int qq = 0; qq < 4; ++qq) {
    base[qq] = (wave * 4 + qq) * 1024;
    int off = base[qq] + lane * 16;
    krow[qq] = off >> 8; kcb[qq] = (off & 255) ^ ((krow[qq] & 15) << 4);
    vrow[qq] = off >> 7; vcb[qq] = (off & 127) ^ ((vrow[qq] & 7) << 4);
  }
#define STAGE(T, B)                                                                             \
  {                                                                                             \
    const int kt = (T) * 64;                                                                    \
    _Pragma("unroll") for (int qq = 0; qq < 4; ++qq) {                                          \
      gll16(kv + (size_t)(kt + krow[qq]) * 2048 + kvh * 128 + (kcb[qq] >> 1), Ks[B] + base[qq]);\
      gll16(vT + (size_t)(kvh * 128 + vrow[qq]) * kvp + kt + (vcb[qq] >> 1), Vs[B] + base[qq]); \
    }                                                                                           \
  }

  f32x4 o[8] = {};
  float m_r[4], l_r[4];
#pragma unroll
  for (int j = 0; j < 4; ++j) { m_r[j] = -1e30f; l_r[j] = 0.0f; }

  STAGE(t0, 0);
  __syncthreads(); // drains prologue loads (vmcnt(0))

  for (int t = t0; t < t1; ++t) {
    const int cur = (t - t0) & 1;
    const int kt0 = t * 64;
    // mask prefetch into regs FIRST (so its waitcnt doesn't drain the stage loads)
    float mf[4][4];
#pragma unroll
    for (int c = 0; c < 4; ++c) {
      int kvi = kt0 + c * 16 + l15;
      const float* mp = mask + (size_t)(qb + lg * 4) * kv_len + min(kvi, kv_len - 1);
#pragma unroll
      for (int j = 0; j < 4; ++j) mf[c][j] = mp[(size_t)j * kv_len];
    }
    // prefetch next tile into the other buffer (drained by the END-of-iter barrier)
    if (t + 1 < t1) STAGE(t + 1, cur ^ 1);
    // S = Q K^T   (each wave: 16 q rows x 64 kv)
    f32x4 s[4] = {};
#pragma unroll
    for (int kk = 0; kk < 4; ++kk)
#pragma unroll
      for (int c = 0; c < 4; ++c) {
        int rr = c * 16 + l15;
        int cb = ((kk * 32 + lg * 8) * 2) ^ ((rr & 15) << 4);
        bf16x8 b = *(const bf16x8*)(Ks[cur] + rr * 256 + cb);
        s[c] = mfma16(qa[kk], b, s[c]);
      }
#pragma unroll
    for (int c = 0; c < 4; ++c) {
      int kvi = kt0 + c * 16 + l15;
      bool valid = kvi < kv_len;
#pragma unroll
      for (int j = 0; j < 4; ++j)
        s[c][j] = valid ? s[c][j] + mf[c][j] : -1e30f;
    }
    // online softmax per q row (rows live in 16-lane groups)
#pragma unroll
    for (int j = 0; j < 4; ++j) {
      float tm = fmaxf(fmaxf(s[0][j], s[1][j]), fmaxf(s[2][j], s[3][j]));
      tm = fmaxf(tm, __shfl_xor(tm, 1));
      tm = fmaxf(tm, __shfl_xor(tm, 2));
      tm = fmaxf(tm, __shfl_xor(tm, 4));
      tm = fmaxf(tm, __shfl_xor(tm, 8));
      float mn = fmaxf(m_r[j], tm);
      float alpha = __expf(m_r[j] - mn);
      m_r[j] = mn;
      float rs = 0.0f;
#pragma unroll
      for (int c = 0; c < 4; ++c) {
        float p = __expf(s[c][j] - mn);
        s[c][j] = p;
        rs += p;
      }
      rs += __shfl_xor(rs, 1);
      rs += __shfl_xor(rs, 2);
      rs += __shfl_xor(rs, 4);
      rs += __shfl_xor(rs, 8);
      l_r[j] = l_r[j] * alpha + rs;
#pragma unroll
      for (int dt = 0; dt < 8; ++dt) o[dt][j] *= alpha;
#pragma unroll
      for (int c = 0; c < 4; ++c) Ps[wave][lg * 4 + j][c * 16 + l15] = f2bf(s[c][j]);
    }
    // O += P V  (P from per-wave LDS; no cross-wave barrier needed)
#pragma unroll
    for (int kk2 = 0; kk2 < 2; ++kk2) {
      bf16x8 a = *(const bf16x8*)&Ps[wave][l15][kk2 * 32 + lg * 8];
#pragma unroll
      for (int dt = 0; dt < 8; ++dt) {
        int rr = dt * 16 + l15;
        int cb = ((kk2 * 32 + lg * 8) * 2) ^ ((rr & 7) << 4);
        bf16x8 b = *(const bf16x8*)(Vs[cur] + rr * 128 + cb);
        o[dt] = mfma16(a, b, o[dt]);
      }
    }
    __syncthreads(); // everyone done reading buf[cur]; stage(t+1) drained
  }
#pragma unroll
  for (int j = 0; j < 4; ++j) {
    int row = qb + lg * 4 + j;
    float* op = pO + (size_t)split * 4194304 + (size_t)row * 4096 + h * 128 + l15;
#pragma unroll
    for (int dt = 0; dt < 8; ++dt) op[dt * 16] = o[dt][j];
    if (l15 == 0) ml[(size_t)split * 32768 + row * 32 + h] = make_float2(m_r[j], l_r[j]);
  }
#undef STAGE
}

// ---------------- merge the 2 KV-splits ----------------
__global__ __launch_bounds__(256) void attn_combine(const float* __restrict__ pO, const float2* __restrict__ ml,
                                                    u16* __restrict__ out) {
  int gw = blockIdx.x * 4 + (threadIdx.x >> 6);
  int lane = threadIdx.x & 63;
  int row = gw >> 5, h = gw & 31;
  float2 A = ml[row * 32 + h];
  float2 B = ml[32768 + row * 32 + h];
  float M = fmaxf(A.x, B.x);
  float e0 = __expf(A.x - M), e1 = __expf(B.x - M);
  float inv = 1.0f / (A.y * e0 + B.y * e1);
  const float* p0 = pO + (size_t)row * 4096 + h * 128 + lane * 2;
  const float* p1 = p0 + 4194304;
  float2 v0 = *(const float2*)p0, v1 = *(const float2*)p1;
  float o0 = (v0.x * e0 + v1.x * e1) * inv;
  float o1 = (v0.y * e0 + v1.y * e1) * inv;
  u16* op = out + (size_t)row * 4096 + h * 128 + lane * 2;
  *(u32*)op = (u32)f2bf(o0) | ((u32)f2bf(o1) << 16);
}

extern "C" void kernel_launch(void* const* d_in, const int* in_sizes, int n_in,
                              void* d_out, int out_size, void* d_ws, size_t ws_size,
                              hipStream_t stream) {
  const float* hidden = (const float*)d_in[0];
  const float* cross = (const float*)d_in[1];
  const float* mask = (const float*)d_in[2];
  const float* w_qkv = (const float*)d_in[3];
  const float* w_o = (const float*)d_in[4];
  const float* q_norm_w = (const float*)d_in[5];
  const float* k_norm_w = (const float*)d_in[6];
  const int q_len = in_sizes[0] / HID;            // 1024
  const int kv_len = in_sizes[1] / HID;           // 6404
  const int kvp = ((kv_len + 127) / 128) * 128;   // 6528
  const int kv_tiles = (kv_len + 63) / 64;        // 101
  const int tps = (kv_tiles + 1) / 2;             // 51

  char* w = (char*)d_ws;
  u16* hB = (u16*)w;    w += (size_t)q_len * HID * 2;
  u16* cB = (u16*)w;    w += (size_t)kv_len * HID * 2;
  u16* wqkvT = (u16*)w; w += (size_t)6144 * 4096 * 2;
  u16* woT = (u16*)w;   w += (size_t)4096 * 4096 * 2;
  u16* qrw = (u16*)w;   w += (size_t)q_len * 4096 * 2;
  u16* kvr = (u16*)w;   w += (size_t)kvp * 2048 * 2;
  u16* vT = (u16*)w;    w += (size_t)1024 * kvp * 2;
  u16* aO = (u16*)w;    w += (size_t)q_len * 4096 * 2;
  // attn partials ALIAS wqkvT (dead after the projection GEMMs): 2x16.78MB pO + 0.5MB ml <= 50.3MB
  float* pO = (float*)wqkvT;
  float2* mlp = (float2*)((char*)wqkvT + 2u * 16777216u);

  cvt_f32_bf16<<<1024, 256, 0, stream>>>(hidden, hB, (size_t)q_len * HID / 4);
  cvt_f32_bf16<<<2048, 256, 0, stream>>>(cross, cB, (size_t)kv_len * HID / 4);
  transpose_cvt<<<dim3(64, 96), 256, 0, stream>>>(w_qkv, wqkvT, 4096, 6144);
  transpose_cvt<<<dim3(64, 64), 256, 0, stream>>>(w_o, woT, 4096, 4096);

  // q projection + RMS norm (SCALE folded in)
  gemm_bt<0, 0><<<dim3(q_len / 128, 32), 256, 0, stream>>>(hB, wqkvT, qrw, 4096, 4096, 0, 0);
  rmsnorm_kernel<<<(q_len * 32 + 3) / 4, 256, 0, stream>>>(qrw, q_norm_w, q_len * 32, 32, 4096, SCALE_Q);

  // kv projection (rows clamped to kv_len, padded rows stored as dups) + k norm + V transpose
  gemm_bt<0, 1><<<dim3(kvp / 128, 16), 256, 0, stream>>>(cB, wqkvT + (size_t)4096 * 4096, kvr, 2048, 4096, kv_len, kvp);
  rmsnorm_kernel<<<(kvp * 8 + 3) / 4, 256, 0, stream>>>(kvr, k_norm_w, kvp * 8, 8, 2048, 1.0f);
  transpose_bf<<<dim3(kvp / 64, 16), 256, 0, stream>>>(kvr, vT, 2048, 1024, kvp);

  attn_kernel<<<dim3(q_len / 64, HH, 2), 256, 0, stream>>>(qrw, kvr, vT, mask, pO, mlp, kv_len, kv_tiles, kvp, tps);
  attn_combine<<<(q_len * HH) / 4, 256, 0, stream>>>(pO, mlp, aO);

  gemm_bt<1, 0><<<dim3(q_len / 128, 32), 256, 0, stream>>>(aO, woT, d_out, 4096, 4096, 0, 0);
}